// Round 5
// baseline (416.742 us; speedup 1.0000x reference)
//
#include <hip/hip_runtime.h>
#include <cstdint>
#include <cstddef>

typedef __attribute__((ext_vector_type(8))) short short8;     // 8 x 16-bit (4 VGPRs)
typedef __attribute__((ext_vector_type(8))) _Float16 f16x8;   // fp16 MFMA frag
typedef __attribute__((ext_vector_type(4))) float f32x4;
typedef __attribute__((ext_vector_type(4))) unsigned short u16x4;
typedef unsigned short u16;

#define FP_  2048
#define AD_  1024
#define BB_  512
#define TT_  50000
#define BETA_ 0.125f

// ---------- fp32 -> bf16 (RNE) helpers ----------
__device__ __forceinline__ u16 f2bf(float x){
  uint32_t u = __builtin_bit_cast(uint32_t, x);
  u = (u + 0x7fffu + ((u >> 16) & 1u)) >> 16;
  return (u16)u;
}
__device__ __forceinline__ float bf2f(u16 h){
  uint32_t u = ((uint32_t)h) << 16;
  return __builtin_bit_cast(float, u);
}
__device__ __forceinline__ u16 f2h_bits(float x){
  _Float16 h = (_Float16)x;            // RNE
  return __builtin_bit_cast(u16, h);
}

// ---------- async global->LDS, 16B per lane ----------
__device__ __forceinline__ void gload_lds16(const void* g, void* l){
  __builtin_amdgcn_global_load_lds((const __attribute__((address_space(1))) void*)g,
                                   (__attribute__((address_space(3))) void*)l,
                                   16, 0, 0);
}

#define SB   __builtin_amdgcn_s_barrier()
#define SCH  __builtin_amdgcn_sched_barrier(0)
#define WAIT_LGKM0 asm volatile("s_waitcnt lgkmcnt(0)" ::: "memory")
#define WAIT_VM(n) asm volatile("s_waitcnt vmcnt(" #n ")" ::: "memory")

// ---------- elementwise fp32 -> (hi,lo) bf16 ----------
__global__ void conv_hilo_k(const float* __restrict__ src, u16* __restrict__ hi,
                            u16* __restrict__ lo, int n){
  int i = (blockIdx.x * blockDim.x + threadIdx.x) * 4;
  if (i >= n) return;
  f32x4 v = *reinterpret_cast<const f32x4*>(src + i);
  u16x4 h, l;
  #pragma unroll
  for (int e = 0; e < 4; ++e){
    float x = v[e];
    u16 hs = f2bf(x);
    h[e] = hs;
    l[e] = f2bf(x - bf2f(hs));
  }
  *reinterpret_cast<u16x4*>(hi + i) = h;
  *reinterpret_cast<u16x4*>(lo + i) = l;
}

// ---------- W[R][C] -> out[C][R] with hi/lo split (LDS tile transpose) ----------
__global__ void conv_hilo_T_k(const float* __restrict__ W, u16* __restrict__ hiT,
                              u16* __restrict__ loT, int R, int C){
  __shared__ float tile[32][33];
  int c0 = blockIdx.x * 32;
  int r0 = blockIdx.y * 32;
  int tx = threadIdx.x;   // 0..31
  int ty = threadIdx.y;   // 0..7
  #pragma unroll
  for (int i = 0; i < 32; i += 8)
    tile[ty + i][tx] = W[(size_t)(r0 + ty + i) * C + c0 + tx];
  __syncthreads();
  #pragma unroll
  for (int i = 0; i < 32; i += 8){
    float x = tile[tx][ty + i];              // = W[r0+tx][c0+ty+i]
    u16 hs = f2bf(x);
    size_t o = (size_t)(c0 + ty + i) * R + r0 + tx;   // out[f][a]
    hiT[o] = hs;
    loT[o] = f2bf(x - bf2f(hs));
  }
}

// ---------- c[b] = dot(Xi[b,:], b_temp) : one wave per row ----------
__global__ void dot_rows_k(const float* __restrict__ Xi, const float* __restrict__ bt,
                           float* __restrict__ c, int K){
  int row  = blockIdx.x * 4 + (threadIdx.x >> 6);
  int lane = threadIdx.x & 63;
  float s = 0.f;
  for (int a = lane; a < K; a += 64) s += Xi[(size_t)row * K + a] * bt[a];
  #pragma unroll
  for (int off = 32; off; off >>= 1) s += __shfl_down(s, off);
  if (lane == 0) c[row] = s;
}

// ---------- split-bf16 small GEMM: C = A·B^T + colBias (3-term hi/lo) ----------
// OUT16: 0=none, 1=bf16 hi/lo pair, 2=fp16 hi/lo pair
template<int TM, int TN, int FM, int FN, int OUT16>
__global__ __launch_bounds__(256, 2)
void gemm_hilo(const u16* __restrict__ Ahi, const u16* __restrict__ Alo,
               const u16* __restrict__ Bhi, const u16* __restrict__ Blo,
               int M, int N, int K,
               float* __restrict__ Cf, u16* __restrict__ Chi, u16* __restrict__ Clo,
               const float* __restrict__ colBias)
{
  constexpr int BK = 32;
  constexpr int WM = TM / (16 * FM);
  constexpr int WN = TN / (16 * FN);
  static_assert(WM * WN == 4, "4 waves / 256 threads");
  constexpr int BUFE = (2 * TM + 2 * TN) * BK;

  __shared__ __align__(16) u16 lds[2 * BUFE];

  const int m0 = blockIdx.x * TM;
  const int n0 = blockIdx.y * TN;

  const int tid  = threadIdx.x;
  const int w    = tid >> 6;
  const int lane = tid & 63;
  const int lr   = lane & 15;
  const int lg   = lane >> 4;
  const int wm   = w / WN;
  const int wn   = w % WN;

  const int rrA = tid >> 2;     // 0..63
  const int chA = tid & 3;      // 16B chunk

  short8 ra[2], rb[2];

  f32x4 acc[FM][FN];
  #pragma unroll
  for (int i = 0; i < FM; ++i)
    #pragma unroll
    for (int j = 0; j < FN; ++j)
      acc[i][j] = (f32x4){0.f, 0.f, 0.f, 0.f};

  auto stage_load = [&](int k0){
    int gm = m0 + rrA;
    ra[0] = *reinterpret_cast<const short8*>(Ahi + (size_t)gm * K + k0 + chA * 8);
    ra[1] = *reinterpret_cast<const short8*>(Alo + (size_t)gm * K + k0 + chA * 8);
    int gn = n0 + rrA; if (gn > N - 1) gn = N - 1;
    rb[0] = *reinterpret_cast<const short8*>(Bhi + (size_t)gn * K + k0 + chA * 8);
    rb[1] = *reinterpret_cast<const short8*>(Blo + (size_t)gn * K + k0 + chA * 8);
  };
  auto stage_store = [&](int buf){
    u16* As_hi = lds + buf * BUFE;
    u16* As_lo = As_hi + TM * BK;
    u16* Bs_hi = As_hi + 2 * TM * BK;
    u16* Bs_lo = As_hi + 2 * TM * BK + TN * BK;
    int row = rrA;
    int sw  = (chA ^ ((row >> 1) & 3)) << 3;
    *reinterpret_cast<short8*>(As_hi + row * BK + sw) = ra[0];
    *reinterpret_cast<short8*>(As_lo + row * BK + sw) = ra[1];
    *reinterpret_cast<short8*>(Bs_hi + row * BK + sw) = rb[0];
    *reinterpret_cast<short8*>(Bs_lo + row * BK + sw) = rb[1];
  };

  const int NT = K / BK;
  stage_load(0);
  stage_store(0);
  __syncthreads();

  int cur = 0;
  for (int t = 0; t < NT; ++t){
    const bool have_next = (t + 1 < NT);
    if (have_next) stage_load((t + 1) * BK);

    u16* As_hi = lds + cur * BUFE;
    u16* As_lo = As_hi + TM * BK;
    u16* Bs_hi = As_hi + 2 * TM * BK;
    u16* Bs_lo = As_hi + 2 * TM * BK + TN * BK;

    short8 ah[FM], al[FM], bh[FN], bl[FN];
    #pragma unroll
    for (int i = 0; i < FM; ++i){
      int row = wm * FM * 16 + i * 16 + lr;
      int off = row * BK + ((lg ^ ((row >> 1) & 3)) << 3);
      ah[i] = *reinterpret_cast<short8*>(As_hi + off);
      al[i] = *reinterpret_cast<short8*>(As_lo + off);
    }
    #pragma unroll
    for (int j = 0; j < FN; ++j){
      int row = wn * FN * 16 + j * 16 + lr;
      int off = row * BK + ((lg ^ ((row >> 1) & 3)) << 3);
      bh[j] = *reinterpret_cast<short8*>(Bs_hi + off);
      bl[j] = *reinterpret_cast<short8*>(Bs_lo + off);
    }
    #pragma unroll
    for (int i = 0; i < FM; ++i)
      #pragma unroll
      for (int j = 0; j < FN; ++j){
        acc[i][j] = __builtin_amdgcn_mfma_f32_16x16x32_bf16(ah[i], bh[j], acc[i][j], 0, 0, 0);
        acc[i][j] = __builtin_amdgcn_mfma_f32_16x16x32_bf16(ah[i], bl[j], acc[i][j], 0, 0, 0);
        acc[i][j] = __builtin_amdgcn_mfma_f32_16x16x32_bf16(al[i], bh[j], acc[i][j], 0, 0, 0);
      }

    if (have_next){
      __builtin_amdgcn_sched_barrier(0);
      stage_store(cur ^ 1);
      __syncthreads();
    }
    cur ^= 1;
  }

  #pragma unroll
  for (int i = 0; i < FM; ++i){
    int rbase = m0 + wm * FM * 16 + i * 16 + lg * 4;
    #pragma unroll
    for (int j = 0; j < FN; ++j){
      int gcol = n0 + wn * FN * 16 + j * 16 + lr;
      if (gcol < N){
        float cb = colBias ? colBias[gcol] : 0.f;
        #pragma unroll
        for (int r = 0; r < 4; ++r){
          int grow = rbase + r;
          float v = acc[i][j][r] + cb;
          size_t idx = (size_t)grow * N + gcol;
          if (Cf) Cf[idx] = v;
          if constexpr (OUT16 == 1){
            u16 hs = f2bf(v);
            Chi[idx] = hs;
            Clo[idx] = f2bf(v - bf2f(hs));
          } else if constexpr (OUT16 == 2){
            _Float16 h = (_Float16)v;
            Chi[idx] = __builtin_bit_cast(u16, h);
            Clo[idx] = f2h_bits(v - (float)h);
          }
        }
      }
    }
  }
}

// ---------- BIG GEMM, phase-split counted-vmcnt schedule (T3+T4+T5) ----------
// out = alpha*(A·B^T + rowAdd); A = Y as SINGLE fp16 [512][2048], B = fp32
// templates converted to fp16 in the staging pipeline (error << bf16-ulp
// comparison floor; threshold 0.1025, floor 0.03125).
// BM=128 x BN=256, BK=32 half-tiles, 8 waves (2Mx4N, wave tile 64x64).
// 4 LDS slots x 24KB = 96KB. A: global_load_lds 2 halves ahead (L2-resident).
// B: global->reg 2 halves ahead, convert+ds_write 1 half ahead.
// Per-wave issue queue per half: [B:4, A:1]. Steady state entering iter(h):
// [B(h+1):4, A(h+1):1]; after phase-A +B(h+2):4, phase-B +A(h+2):1 = 10.
//   WAIT_VM(6) -> B(h+1) retired (convert safe); WAIT_VM(5) -> A(h+1) landed.
// Tail (no new issues): WAIT_VM(1) / WAIT_VM(0).
__global__ __launch_bounds__(512, 1)
void gemm_big(const u16* __restrict__ Ah,      // fp16 bits [512][2048]
              const float* __restrict__ Bf,    // [50000][2048]
              float* __restrict__ C,
              const float* __restrict__ rowAdd, float alpha)
{
  constexpr int TM = 128, TN = 256, BK = 32;
  constexpr int K = FP_, NN = TT_;
  constexpr int HALVES = K / BK;               // 64
  constexpr int SLOT_A = TM * BK;              // 4096 u16 = 8KB
  constexpr int SLOT_B = TN * BK;              // 8192 u16 = 16KB
  constexpr int SLOT_E = SLOT_A + SLOT_B;      // 12288 u16 = 24KB

  __shared__ __align__(16) u16 lds[4 * SLOT_E];   // 96KB

  // bijective XCD grouping: xcd<4 own 25 N-strips, xcd>=4 own 24 (196 total).
  // Within an XCD, g = (s<<2)|mt -> the 4 M-blocks of a strip are concurrent
  // on 4 CUs of the same XCD (B-strip L2 reuse).
  int id  = blockIdx.x;
  int xcd = id & 7;
  int g   = id >> 3;          // 0..99
  int mt  = g & 3;            // 4 M-tiles of 128
  int s   = g >> 2;           // 0..24
  int strips = (xcd < 4) ? 25 : 24;
  if (s >= strips) return;
  int nt = ((xcd < 4) ? xcd * 25 : 100 + (xcd - 4) * 24) + s;   // 0..195
  const int m0 = mt * TM;
  const int n0 = nt * TN;

  const int tid  = threadIdx.x;
  const int w    = tid >> 6;        // 0..7
  const int lane = tid & 63;
  const int lr   = lane & 15;
  const int lg   = lane >> 4;
  const int wm   = w >> 2;          // 0..1
  const int wn   = w & 3;           // 0..3

  const int rowB = tid >> 3;        // 0..63
  const int c4   = tid & 7;         // f32x4 chunk in a 32-float row

  // ---- staging helpers ----
  auto issueA = [&](int k0, u16* slotp){
    int rloc = lane >> 2;           // 0..15
    int cc   = lane & 3;
    int row  = w * 16 + rloc;
    int sc   = cc ^ ((row >> 1) & 3);             // inverse swizzle on source
    const u16* gh = Ah + (size_t)(m0 + row) * K + k0 + sc * 8;
    gload_lds16(gh, slotp + w * 16 * BK);          // wave-uniform dest + lane*16B
  };
  auto issueB = [&](int k0, f32x4 (&rb)[4]){
    #pragma unroll
    for (int p = 0; p < 4; ++p){
      int gn = n0 + rowB + p * 64; if (gn > NN - 1) gn = NN - 1;
      rb[p] = *reinterpret_cast<const f32x4*>(Bf + (size_t)gn * K + k0 + c4 * 4);
    }
  };
  auto writeB = [&](u16* slotp, f32x4 (&rb)[4]){
    u16* bb = slotp + SLOT_A;
    #pragma unroll
    for (int p = 0; p < 4; ++p){
      int row = rowB + p * 64;
      u16x4 hv;
      #pragma unroll
      for (int e = 0; e < 4; ++e) hv[e] = f2h_bits(rb[p][e]);
      int q   = c4 >> 1;
      int off = row * BK + ((q ^ ((row >> 1) & 3)) << 3) + (c4 & 1) * 4;
      *reinterpret_cast<u16x4*>(bb + off) = hv;
    }
  };

  f32x4 acc[4][4];
  #pragma unroll
  for (int i = 0; i < 4; ++i)
    #pragma unroll
    for (int j = 0; j < 4; ++j)
      acc[i][j] = (f32x4){0.f, 0.f, 0.f, 0.f};

  f16x8 b[4], a[2];

  auto readB = [&](u16* sp){
    u16* bb = sp + SLOT_A;
    #pragma unroll
    for (int j = 0; j < 4; ++j){
      int row = wn * 64 + j * 16 + lr;
      int off = row * BK + ((lg ^ ((row >> 1) & 3)) << 3);
      b[j] = __builtin_bit_cast(f16x8, *reinterpret_cast<short8*>(bb + off));
    }
  };
  auto readA = [&](u16* sp, int i0){
    #pragma unroll
    for (int ii = 0; ii < 2; ++ii){
      int row = wm * 64 + (i0 + ii) * 16 + lr;
      int off = row * BK + ((lg ^ ((row >> 1) & 3)) << 3);
      a[ii] = __builtin_bit_cast(f16x8, *reinterpret_cast<short8*>(sp + off));
    }
  };

#define MMA_PHASE(I0)                                                              \
  __builtin_amdgcn_s_setprio(1);                                                   \
  _Pragma("unroll")                                                                \
  for (int ii = 0; ii < 2; ++ii){                                                  \
    _Pragma("unroll")                                                              \
    for (int j = 0; j < 4; ++j){                                                   \
      acc[(I0)+ii][j] = __builtin_amdgcn_mfma_f32_16x16x32_f16(a[ii], b[j], acc[(I0)+ii][j], 0, 0, 0); \
    }                                                                              \
  }                                                                                \
  __builtin_amdgcn_s_setprio(0);

  f32x4 rbA[4], rbB[4];

  // ---- prologue: stage halves 0,1; convert B(0); confirm slot0 ----
  issueB(0, rbA);               // 4
  issueA(0, lds);               // 1
  issueB(BK, rbB);              // 4
  issueA(BK, lds + SLOT_E);     // 1   queue: [B0:4, A0:1, B1:4, A1:1] = 10
  SCH;
  WAIT_VM(6);                   // B(0) retired
  writeB(lds, rbA);
  WAIT_LGKM0;
  WAIT_VM(5);                   // A(0) landed   (remain [B1:4, A1:1] = 5)
  SB; SCH;

  // ---- main loop: iter(h) computes half h; issues h+2; publishes h+1 ----
  auto iter = [&](int h, f32x4 (&rbI)[4], f32x4 (&rbC)[4]){
    u16* sp = lds + (size_t)(h & 3) * SLOT_E;
    // ---- phase A: frags + B prefetch, MFMA i={0,1} ----
    readB(sp);
    readA(sp, 0);
    if (h + 2 < HALVES) issueB((h + 2) * BK, rbI);
    SB; SCH;
    WAIT_LGKM0; SCH;
    MMA_PHASE(0);
    SB; SCH;
    // ---- phase B: frags + A prefetch + B(h+1) convert/publish, MFMA i={2,3} ----
    readA(sp, 2);
    if (h + 2 < HALVES) issueA((h + 2) * BK, lds + (size_t)((h + 2) & 3) * SLOT_E);
    SCH;                                        // pin issues above the counted waits
    if (h + 1 < HALVES){
      if (h + 2 < HALVES) { WAIT_VM(6); } else { WAIT_VM(1); }   // B(h+1) retired
      writeB(lds + (size_t)((h + 1) & 3) * SLOT_E, rbC);
      WAIT_LGKM0;                                                // retire my ds_writes
      if (h + 2 < HALVES) { WAIT_VM(5); } else { WAIT_VM(0); }   // A(h+1) landed
    }
    SB; SCH;
    WAIT_LGKM0; SCH;
    MMA_PHASE(2);
    SB; SCH;
  };

  for (int hh = 0; hh < HALVES; hh += 2){
    iter(hh,     rbA, rbB);
    iter(hh + 1, rbB, rbA);
  }

  // ---- epilogue: row=(lane>>4)*4+reg (A index), col=lane&15 (B index) ----
  #pragma unroll
  for (int i = 0; i < 4; ++i){
    int rbase = m0 + wm * 64 + i * 16 + lg * 4;
    #pragma unroll
    for (int j = 0; j < 4; ++j){
      int gcol = n0 + wn * 64 + j * 16 + lr;
      if (gcol < NN){
        #pragma unroll
        for (int r = 0; r < 4; ++r){
          int grow = rbase + r;
          float v = (acc[i][j][r] + rowAdd[grow]) * alpha;
          C[(size_t)grow * NN + gcol] = v;
        }
      }
    }
  }
#undef MMA_PHASE
}

extern "C" void kernel_launch(void* const* d_in, const int* in_sizes, int n_in,
                              void* d_out, int out_size, void* d_ws, size_t ws_size,
                              hipStream_t stream){
  (void)in_sizes; (void)n_in; (void)out_size; (void)ws_size;
  const float* m    = (const float*)d_in[0];   // [512][2048]
  const float* tpl  = (const float*)d_in[1];   // [50000][2048]
  const float* Wmol = (const float*)d_in[2];   // [1024][2048]
  const float* bmol = (const float*)d_in[3];   // [1024]
  const float* Wtmp = (const float*)d_in[4];   // [1024][2048]
  const float* btmp = (const float*)d_in[5];   // [1024]
  float* out = (float*)d_out;                  // [512][50000]

  uint8_t* wp = (uint8_t*)d_ws;
  auto carve = [&](size_t bytes) -> void* {
    void* p = (void*)wp;
    wp += (bytes + 255) & ~(size_t)255;
    return p;
  };
  u16* m_hi   = (u16*)carve((size_t)BB_ * FP_ * 2);
  u16* m_lo   = (u16*)carve((size_t)BB_ * FP_ * 2);
  u16* wm_hi  = (u16*)carve((size_t)AD_ * FP_ * 2);
  u16* wm_lo  = (u16*)carve((size_t)AD_ * FP_ * 2);
  u16* wtT_hi = (u16*)carve((size_t)FP_ * AD_ * 2);
  u16* wtT_lo = (u16*)carve((size_t)FP_ * AD_ * 2);
  float* Xi   = (float*)carve((size_t)BB_ * AD_ * 4);
  u16* Xi_hi  = (u16*)carve((size_t)BB_ * AD_ * 2);
  u16* Xi_lo  = (u16*)carve((size_t)BB_ * AD_ * 2);
  u16* Y_hi   = (u16*)carve((size_t)BB_ * FP_ * 2);   // fp16 bits
  u16* Y_lo   = (u16*)carve((size_t)BB_ * FP_ * 2);   // fp16 bits (unused by big gemm)
  float* cvec = (float*)carve((size_t)BB_ * 4);

  // 1) split inputs to bf16 hi/lo (W_temp also transposed to [FP][A])
  conv_hilo_k<<<(BB_ * FP_ / 4 + 255) / 256, 256, 0, stream>>>(m, m_hi, m_lo, BB_ * FP_);
  conv_hilo_k<<<(AD_ * FP_ / 4 + 255) / 256, 256, 0, stream>>>(Wmol, wm_hi, wm_lo, AD_ * FP_);
  conv_hilo_T_k<<<dim3(FP_ / 32, AD_ / 32), dim3(32, 8), 0, stream>>>(Wtmp, wtT_hi, wtT_lo, AD_, FP_);

  // 2) Xi = m @ W_mol^T + b_mol   [512 x 1024], K=2048  (fp32 + bf16 hi/lo out)
  gemm_hilo<64, 64, 2, 2, 1><<<dim3(BB_ / 64, AD_ / 64), 256, 0, stream>>>(
      m_hi, m_lo, wm_hi, wm_lo, BB_, AD_, FP_,
      Xi, Xi_hi, Xi_lo, bmol);

  // 3) c[b] = Xi[b,:] . b_temp
  dot_rows_k<<<BB_ / 4, 256, 0, stream>>>(Xi, btmp, cvec, AD_);

  // 4) Y = Xi @ W_temp   [512 x 2048], K=1024  -> fp16 hi/lo (big gemm uses hi only)
  gemm_hilo<64, 64, 2, 2, 2><<<dim3(BB_ / 64, FP_ / 64), 256, 0, stream>>>(
      Xi_hi, Xi_lo, wtT_hi, wtT_lo, BB_, FP_, AD_,
      nullptr, Y_hi, Y_lo, nullptr);

  // 5) out = BETA * (Y @ templates^T + c)   [512 x 50000], K=2048
  //    800 blocks = 8 XCD residues x (4 M-tiles x 25 strip-slots); 16 masked.
  gemm_big<<<800, 512, 0, stream>>>(Y_hi, tpl, out, cvec, BETA_);
}

// Round 6
// 341.568 us; speedup vs baseline: 1.2201x; 1.2201x over previous
//
#include <hip/hip_runtime.h>
#include <cstdint>
#include <cstddef>

typedef __attribute__((ext_vector_type(8))) short short8;     // 8 x 16-bit (4 VGPRs)
typedef __attribute__((ext_vector_type(8))) _Float16 f16x8;   // fp16 MFMA frag
typedef __attribute__((ext_vector_type(4))) float f32x4;
typedef __attribute__((ext_vector_type(4))) unsigned short u16x4;
typedef unsigned short u16;

#define FP_  2048
#define AD_  1024
#define BB_  512
#define TT_  50000
#define BETA_ 0.125f

// ---------- fp32 -> bf16 (RNE) helpers ----------
__device__ __forceinline__ u16 f2bf(float x){
  uint32_t u = __builtin_bit_cast(uint32_t, x);
  u = (u + 0x7fffu + ((u >> 16) & 1u)) >> 16;
  return (u16)u;
}
__device__ __forceinline__ float bf2f(u16 h){
  uint32_t u = ((uint32_t)h) << 16;
  return __builtin_bit_cast(float, u);
}
__device__ __forceinline__ u16 f2h_bits(float x){
  _Float16 h = (_Float16)x;            // RNE
  return __builtin_bit_cast(u16, h);
}

// ---------- async global->LDS, 16B per lane ----------
__device__ __forceinline__ void gload_lds16(const void* g, void* l){
  __builtin_amdgcn_global_load_lds((const __attribute__((address_space(1))) void*)g,
                                   (__attribute__((address_space(3))) void*)l,
                                   16, 0, 0);
}

#define SB   __builtin_amdgcn_s_barrier()
#define SCH  __builtin_amdgcn_sched_barrier(0)
#define WAIT_LGKM0 asm volatile("s_waitcnt lgkmcnt(0)" ::: "memory")
#define WAIT_VM(n) asm volatile("s_waitcnt vmcnt(" #n ")" ::: "memory")

// ---------- elementwise fp32 -> (hi,lo) bf16 ----------
__global__ void conv_hilo_k(const float* __restrict__ src, u16* __restrict__ hi,
                            u16* __restrict__ lo, int n){
  int i = (blockIdx.x * blockDim.x + threadIdx.x) * 4;
  if (i >= n) return;
  f32x4 v = *reinterpret_cast<const f32x4*>(src + i);
  u16x4 h, l;
  #pragma unroll
  for (int e = 0; e < 4; ++e){
    float x = v[e];
    u16 hs = f2bf(x);
    h[e] = hs;
    l[e] = f2bf(x - bf2f(hs));
  }
  *reinterpret_cast<u16x4*>(hi + i) = h;
  *reinterpret_cast<u16x4*>(lo + i) = l;
}

// ---------- W[R][C] -> out[C][R] with hi/lo split (LDS tile transpose) ----------
__global__ void conv_hilo_T_k(const float* __restrict__ W, u16* __restrict__ hiT,
                              u16* __restrict__ loT, int R, int C){
  __shared__ float tile[32][33];
  int c0 = blockIdx.x * 32;
  int r0 = blockIdx.y * 32;
  int tx = threadIdx.x;   // 0..31
  int ty = threadIdx.y;   // 0..7
  #pragma unroll
  for (int i = 0; i < 32; i += 8)
    tile[ty + i][tx] = W[(size_t)(r0 + ty + i) * C + c0 + tx];
  __syncthreads();
  #pragma unroll
  for (int i = 0; i < 32; i += 8){
    float x = tile[tx][ty + i];              // = W[r0+tx][c0+ty+i]
    u16 hs = f2bf(x);
    size_t o = (size_t)(c0 + ty + i) * R + r0 + tx;   // out[f][a]
    hiT[o] = hs;
    loT[o] = f2bf(x - bf2f(hs));
  }
}

// ---------- c[b] = dot(Xi[b,:], b_temp) : one wave per row ----------
__global__ void dot_rows_k(const float* __restrict__ Xi, const float* __restrict__ bt,
                           float* __restrict__ c, int K){
  int row  = blockIdx.x * 4 + (threadIdx.x >> 6);
  int lane = threadIdx.x & 63;
  float s = 0.f;
  for (int a = lane; a < K; a += 64) s += Xi[(size_t)row * K + a] * bt[a];
  #pragma unroll
  for (int off = 32; off; off >>= 1) s += __shfl_down(s, off);
  if (lane == 0) c[row] = s;
}

// ---------- split-bf16 small GEMM: C = A·B^T + colBias (3-term hi/lo) ----------
// OUT16: 0=none, 1=bf16 hi/lo pair, 2=fp16 hi/lo pair
template<int TM, int TN, int FM, int FN, int OUT16>
__global__ __launch_bounds__(256, 2)
void gemm_hilo(const u16* __restrict__ Ahi, const u16* __restrict__ Alo,
               const u16* __restrict__ Bhi, const u16* __restrict__ Blo,
               int M, int N, int K,
               float* __restrict__ Cf, u16* __restrict__ Chi, u16* __restrict__ Clo,
               const float* __restrict__ colBias)
{
  constexpr int BK = 32;
  constexpr int WM = TM / (16 * FM);
  constexpr int WN = TN / (16 * FN);
  static_assert(WM * WN == 4, "4 waves / 256 threads");
  constexpr int BUFE = (2 * TM + 2 * TN) * BK;

  __shared__ __align__(16) u16 lds[2 * BUFE];

  const int m0 = blockIdx.x * TM;
  const int n0 = blockIdx.y * TN;

  const int tid  = threadIdx.x;
  const int w    = tid >> 6;
  const int lane = tid & 63;
  const int lr   = lane & 15;
  const int lg   = lane >> 4;
  const int wm   = w / WN;
  const int wn   = w % WN;

  const int rrA = tid >> 2;     // 0..63
  const int chA = tid & 3;      // 16B chunk

  short8 ra[2], rb[2];

  f32x4 acc[FM][FN];
  #pragma unroll
  for (int i = 0; i < FM; ++i)
    #pragma unroll
    for (int j = 0; j < FN; ++j)
      acc[i][j] = (f32x4){0.f, 0.f, 0.f, 0.f};

  auto stage_load = [&](int k0){
    int gm = m0 + rrA;
    ra[0] = *reinterpret_cast<const short8*>(Ahi + (size_t)gm * K + k0 + chA * 8);
    ra[1] = *reinterpret_cast<const short8*>(Alo + (size_t)gm * K + k0 + chA * 8);
    int gn = n0 + rrA; if (gn > N - 1) gn = N - 1;
    rb[0] = *reinterpret_cast<const short8*>(Bhi + (size_t)gn * K + k0 + chA * 8);
    rb[1] = *reinterpret_cast<const short8*>(Blo + (size_t)gn * K + k0 + chA * 8);
  };
  auto stage_store = [&](int buf){
    u16* As_hi = lds + buf * BUFE;
    u16* As_lo = As_hi + TM * BK;
    u16* Bs_hi = As_hi + 2 * TM * BK;
    u16* Bs_lo = As_hi + 2 * TM * BK + TN * BK;
    int row = rrA;
    int sw  = (chA ^ ((row >> 1) & 3)) << 3;
    *reinterpret_cast<short8*>(As_hi + row * BK + sw) = ra[0];
    *reinterpret_cast<short8*>(As_lo + row * BK + sw) = ra[1];
    *reinterpret_cast<short8*>(Bs_hi + row * BK + sw) = rb[0];
    *reinterpret_cast<short8*>(Bs_lo + row * BK + sw) = rb[1];
  };

  const int NT = K / BK;
  stage_load(0);
  stage_store(0);
  __syncthreads();

  int cur = 0;
  for (int t = 0; t < NT; ++t){
    const bool have_next = (t + 1 < NT);
    if (have_next) stage_load((t + 1) * BK);

    u16* As_hi = lds + cur * BUFE;
    u16* As_lo = As_hi + TM * BK;
    u16* Bs_hi = As_hi + 2 * TM * BK;
    u16* Bs_lo = As_hi + 2 * TM * BK + TN * BK;

    short8 ah[FM], al[FM], bh[FN], bl[FN];
    #pragma unroll
    for (int i = 0; i < FM; ++i){
      int row = wm * FM * 16 + i * 16 + lr;
      int off = row * BK + ((lg ^ ((row >> 1) & 3)) << 3);
      ah[i] = *reinterpret_cast<short8*>(As_hi + off);
      al[i] = *reinterpret_cast<short8*>(As_lo + off);
    }
    #pragma unroll
    for (int j = 0; j < FN; ++j){
      int row = wn * FN * 16 + j * 16 + lr;
      int off = row * BK + ((lg ^ ((row >> 1) & 3)) << 3);
      bh[j] = *reinterpret_cast<short8*>(Bs_hi + off);
      bl[j] = *reinterpret_cast<short8*>(Bs_lo + off);
    }
    #pragma unroll
    for (int i = 0; i < FM; ++i)
      #pragma unroll
      for (int j = 0; j < FN; ++j){
        acc[i][j] = __builtin_amdgcn_mfma_f32_16x16x32_bf16(ah[i], bh[j], acc[i][j], 0, 0, 0);
        acc[i][j] = __builtin_amdgcn_mfma_f32_16x16x32_bf16(ah[i], bl[j], acc[i][j], 0, 0, 0);
        acc[i][j] = __builtin_amdgcn_mfma_f32_16x16x32_bf16(al[i], bh[j], acc[i][j], 0, 0, 0);
      }

    if (have_next){
      __builtin_amdgcn_sched_barrier(0);
      stage_store(cur ^ 1);
      __syncthreads();
    }
    cur ^= 1;
  }

  #pragma unroll
  for (int i = 0; i < FM; ++i){
    int rbase = m0 + wm * FM * 16 + i * 16 + lg * 4;
    #pragma unroll
    for (int j = 0; j < FN; ++j){
      int gcol = n0 + wn * FN * 16 + j * 16 + lr;
      if (gcol < N){
        float cb = colBias ? colBias[gcol] : 0.f;
        #pragma unroll
        for (int r = 0; r < 4; ++r){
          int grow = rbase + r;
          float v = acc[i][j][r] + cb;
          size_t idx = (size_t)grow * N + gcol;
          if (Cf) Cf[idx] = v;
          if constexpr (OUT16 == 1){
            u16 hs = f2bf(v);
            Chi[idx] = hs;
            Clo[idx] = f2bf(v - bf2f(hs));
          } else if constexpr (OUT16 == 2){
            _Float16 h = (_Float16)v;
            Chi[idx] = __builtin_bit_cast(u16, h);
            Clo[idx] = f2h_bits(v - (float)h);
          }
        }
      }
    }
  }
}

// ---------- BIG GEMM, streaming-B regime: deep MLP + 4 blocks/CU ----------
// out = alpha*(A·B^T + rowAdd); A = Y fp16 [512][2048] (L2-resident),
// B = fp32 templates converted to fp16 in the staging path (HBM stream).
// TM=64 x TN=128, BK=32, 4 waves (2x2, wave tile 32x64), LDS dbuf 24KB.
// B prefetched 2 tiles ahead into regs (rbE/rbO); A 1 ahead via gload_lds.
// Per-wave vmcnt ledger at steady iter t: [B(t+1):4, A(t+1):1, B(t+2):4]=9
//   post-MFMA: vmcnt(5) -> B(t+1) ready; convert+ds_write; vmcnt(4) -> A(t+1)
//   landed; lgkm0; ONE s_barrier per iter. Tail: vmcnt(1)/vmcnt(0).
__global__ __launch_bounds__(256, 4)
void gemm_big(const u16* __restrict__ Ah,      // fp16 bits [512][2048]
              const float* __restrict__ Bf,    // [50000][2048]
              float* __restrict__ C,
              const float* __restrict__ rowAdd, float alpha)
{
  constexpr int TM = 64, TN = 128, BK = 32;
  constexpr int K = FP_, NN = TT_;
  constexpr int NT = K / BK;                 // 64
  constexpr int SLOT_A = TM * BK;            // 2048 u16 = 4KB
  constexpr int BUFE   = SLOT_A + TN * BK;   // 6144 u16 = 12KB

  __shared__ __align__(16) u16 lds[2 * BUFE];   // 24KB

  // bijective XCD grouping: xcd<7 own 49 N-strips, xcd=7 owns 48 (391 total).
  // g = s*8 + mt -> the 8 M-blocks of a strip run concurrently on one XCD.
  int id  = blockIdx.x;
  int xcd = id & 7;
  int g   = id >> 3;          // 0..391
  int mt  = g & 7;            // 8 M-tiles of 64
  int s   = g >> 3;           // 0..48
  int strips = (xcd < 7) ? 49 : 48;
  if (s >= strips) return;
  int nt = ((xcd < 7) ? xcd * 49 : 343) + s;   // 0..390
  const int m0 = mt * TM;
  const int n0 = nt * TN;

  const int tid  = threadIdx.x;
  const int w    = tid >> 6;        // 0..3
  const int lane = tid & 63;
  const int lr   = lane & 15;
  const int lg   = lane >> 4;
  const int wm   = w >> 1;          // 0..1  (32-row band)
  const int wn   = w & 1;           // 0..1  (64-col band)

  const int rowB = tid >> 3;        // 0..31
  const int c4   = tid & 7;         // f32x4 chunk in a 32-float row

  // ---- staging helpers ----
  auto issueA = [&](int k0, u16* sp){          // 1 vmcnt entry per wave
    int rloc = lane >> 2;                      // 0..15
    int cc   = lane & 3;
    int row  = w * 16 + rloc;
    int sc   = cc ^ ((row >> 1) & 3);          // inverse swizzle on source
    const u16* gh = Ah + (size_t)(m0 + row) * K + k0 + sc * 8;
    gload_lds16(gh, sp + w * 16 * BK);         // wave-uniform dest + lane*16B
  };
  auto issueB = [&](int k0, f32x4 (&rb)[4]){   // 4 vmcnt entries per wave
    #pragma unroll
    for (int p = 0; p < 4; ++p){
      int gn = n0 + rowB + p * 32; if (gn > NN - 1) gn = NN - 1;
      rb[p] = *reinterpret_cast<const f32x4*>(Bf + (size_t)gn * K + k0 + c4 * 4);
    }
  };
  auto writeB = [&](u16* sp, f32x4 (&rb)[4]){
    u16* bb = sp + SLOT_A;
    #pragma unroll
    for (int p = 0; p < 4; ++p){
      int row = rowB + p * 32;
      u16x4 hv;
      #pragma unroll
      for (int e = 0; e < 4; ++e) hv[e] = f2h_bits(rb[p][e]);
      int q   = c4 >> 1;
      int off = row * BK + ((q ^ ((row >> 1) & 3)) << 3) + (c4 & 1) * 4;
      *reinterpret_cast<u16x4*>(bb + off) = hv;
    }
  };

  f32x4 acc[2][4];
  #pragma unroll
  for (int i = 0; i < 2; ++i)
    #pragma unroll
    for (int j = 0; j < 4; ++j)
      acc[i][j] = (f32x4){0.f, 0.f, 0.f, 0.f};

  f32x4 rbE[4], rbO[4];

  // ---- prologue: A(0), B(0), B(1); publish tile 0 ----
  issueA(0, lds);            // 1
  issueB(0, rbE);            // 4
  issueB(BK, rbO);           // 4     queue: [A0:1, B0:4, B1:4] = 9
  SCH;
  WAIT_VM(4);                // A0 + B0 retired (remain B1:4)
  writeB(lds, rbE);
  WAIT_LGKM0;
  SB; SCH;

  // ---- body: one barrier per iter; compute tile t, publish t+1, issue t+2 ----
  auto body = [&](int t, f32x4 (&rbFill)[4], f32x4 (&rbPub)[4]){
    u16* sp  = lds + (t & 1) * BUFE;
    u16* spn = lds + ((t + 1) & 1) * BUFE;
    if (t + 1 < NT) issueA((t + 1) * BK, spn);
    if (t + 2 < NT) issueB((t + 2) * BK, rbFill);

    f16x8 a[2], b[4];
    #pragma unroll
    for (int i = 0; i < 2; ++i){
      int row = wm * 32 + i * 16 + lr;
      int off = row * BK + ((lg ^ ((row >> 1) & 3)) << 3);
      a[i] = __builtin_bit_cast(f16x8, *reinterpret_cast<short8*>(sp + off));
    }
    #pragma unroll
    for (int j = 0; j < 4; ++j){
      int row = wn * 64 + j * 16 + lr;
      int off = row * BK + ((lg ^ ((row >> 1) & 3)) << 3);
      b[j] = __builtin_bit_cast(f16x8, *reinterpret_cast<short8*>(sp + SLOT_A + off));
    }
    WAIT_LGKM0; SCH;
    #pragma unroll
    for (int i = 0; i < 2; ++i)
      #pragma unroll
      for (int j = 0; j < 4; ++j)
        acc[i][j] = __builtin_amdgcn_mfma_f32_16x16x32_f16(a[i], b[j], acc[i][j], 0, 0, 0);
    SCH;

    if (t + 2 < NT){
      WAIT_VM(5);            // B(t+1) retired (leaves A(t+1):1, B(t+2):4)
      writeB(spn, rbPub);
      WAIT_VM(4);            // A(t+1) landed  (leaves B(t+2):4)
      WAIT_LGKM0;
    } else if (t + 1 < NT){
      WAIT_VM(1);            // B(NT-1) retired (leaves A(NT-1):1)
      writeB(spn, rbPub);
      WAIT_VM(0);            // A(NT-1) landed
      WAIT_LGKM0;
    }
    SB; SCH;
  };

  for (int tt = 0; tt < NT; tt += 2){
    body(tt,     rbE, rbO);   // fills rbE with B(tt+2), publishes B(tt+1) from rbO
    body(tt + 1, rbO, rbE);   // fills rbO with B(tt+3), publishes B(tt+2) from rbE
  }

  // ---- epilogue: row=(lane>>4)*4+reg (A index), col=lane&15 (B index) ----
  #pragma unroll
  for (int i = 0; i < 2; ++i){
    int rbase = m0 + wm * 32 + i * 16 + lg * 4;
    #pragma unroll
    for (int j = 0; j < 4; ++j){
      int gcol = n0 + wn * 64 + j * 16 + lr;
      if (gcol < NN){
        #pragma unroll
        for (int r = 0; r < 4; ++r){
          int grow = rbase + r;
          float v = (acc[i][j][r] + rowAdd[grow]) * alpha;
          C[(size_t)grow * NN + gcol] = v;
        }
      }
    }
  }
}

extern "C" void kernel_launch(void* const* d_in, const int* in_sizes, int n_in,
                              void* d_out, int out_size, void* d_ws, size_t ws_size,
                              hipStream_t stream){
  (void)in_sizes; (void)n_in; (void)out_size; (void)ws_size;
  const float* m    = (const float*)d_in[0];   // [512][2048]
  const float* tpl  = (const float*)d_in[1];   // [50000][2048]
  const float* Wmol = (const float*)d_in[2];   // [1024][2048]
  const float* bmol = (const float*)d_in[3];   // [1024]
  const float* Wtmp = (const float*)d_in[4];   // [1024][2048]
  const float* btmp = (const float*)d_in[5];   // [1024]
  float* out = (float*)d_out;                  // [512][50000]

  uint8_t* wp = (uint8_t*)d_ws;
  auto carve = [&](size_t bytes) -> void* {
    void* p = (void*)wp;
    wp += (bytes + 255) & ~(size_t)255;
    return p;
  };
  u16* m_hi   = (u16*)carve((size_t)BB_ * FP_ * 2);
  u16* m_lo   = (u16*)carve((size_t)BB_ * FP_ * 2);
  u16* wm_hi  = (u16*)carve((size_t)AD_ * FP_ * 2);
  u16* wm_lo  = (u16*)carve((size_t)AD_ * FP_ * 2);
  u16* wtT_hi = (u16*)carve((size_t)FP_ * AD_ * 2);
  u16* wtT_lo = (u16*)carve((size_t)FP_ * AD_ * 2);
  float* Xi   = (float*)carve((size_t)BB_ * AD_ * 4);
  u16* Xi_hi  = (u16*)carve((size_t)BB_ * AD_ * 2);
  u16* Xi_lo  = (u16*)carve((size_t)BB_ * AD_ * 2);
  u16* Y_hi   = (u16*)carve((size_t)BB_ * FP_ * 2);   // fp16 bits
  u16* Y_lo   = (u16*)carve((size_t)BB_ * FP_ * 2);   // fp16 bits (unused by big gemm)
  float* cvec = (float*)carve((size_t)BB_ * 4);

  // 1) split inputs to bf16 hi/lo (W_temp also transposed to [FP][A])
  conv_hilo_k<<<(BB_ * FP_ / 4 + 255) / 256, 256, 0, stream>>>(m, m_hi, m_lo, BB_ * FP_);
  conv_hilo_k<<<(AD_ * FP_ / 4 + 255) / 256, 256, 0, stream>>>(Wmol, wm_hi, wm_lo, AD_ * FP_);
  conv_hilo_T_k<<<dim3(FP_ / 32, AD_ / 32), dim3(32, 8), 0, stream>>>(Wtmp, wtT_hi, wtT_lo, AD_, FP_);

  // 2) Xi = m @ W_mol^T + b_mol   [512 x 1024], K=2048  (fp32 + bf16 hi/lo out)
  gemm_hilo<64, 64, 2, 2, 1><<<dim3(BB_ / 64, AD_ / 64), 256, 0, stream>>>(
      m_hi, m_lo, wm_hi, wm_lo, BB_, AD_, FP_,
      Xi, Xi_hi, Xi_lo, bmol);

  // 3) c[b] = Xi[b,:] . b_temp
  dot_rows_k<<<BB_ / 4, 256, 0, stream>>>(Xi, btmp, cvec, AD_);

  // 4) Y = Xi @ W_temp   [512 x 2048], K=1024  -> fp16 hi/lo (big gemm uses hi only)
  gemm_hilo<64, 64, 2, 2, 2><<<dim3(BB_ / 64, FP_ / 64), 256, 0, stream>>>(
      Xi_hi, Xi_lo, wtT_hi, wtT_lo, BB_, FP_, AD_,
      nullptr, Y_hi, Y_lo, nullptr);

  // 5) out = BETA * (Y @ templates^T + c)   [512 x 50000], K=2048
  //    3136 blocks = 8 XCD x 49 strip-slots x 8 M-tiles; 8 masked. 4 blocks/CU.
  gemm_big<<<3136, 256, 0, stream>>>(Y_hi, tpl, out, cvec, BETA_);
}